// Round 10
// baseline (825.779 us; speedup 1.0000x reference)
//
#include <hip/hip_runtime.h>
#include <hip/hip_fp16.h>

#define DEV static __device__ __forceinline__

typedef _Float16 f16;
typedef _Float16 f16x8 __attribute__((ext_vector_type(8)));
typedef _Float16 f16x4 __attribute__((ext_vector_type(4)));
typedef float f32x4 __attribute__((ext_vector_type(4)));

constexpr int BATCH = 16384;
constexpr int D = 1024;
constexpr int HR = 4096;
constexpr int NOUT = 10;

// ---------------------------------------------------------------- fused converts (4 segments, any may be empty)
__global__ void k_conv4(const float* __restrict__ s0, f16* __restrict__ d0, int n0,
                        const float* __restrict__ s1, f16* __restrict__ d1, int n1,
                        const float* __restrict__ s2, f16* __restrict__ d2, int n2,
                        const float* __restrict__ s3, f16* __restrict__ d3, int n3) {
    int i = blockIdx.x * blockDim.x + threadIdx.x;
    const int st = gridDim.x * blockDim.x;
    const int tot = n0 + n1 + n2 + n3;
    for (; i < tot; i += st) {
        const float* s; f16* d; int j = i;
        if (j < n0) { s = s0; d = d0; }
        else {
            j -= n0;
            if (j < n1) { s = s1; d = d1; }
            else {
                j -= n1;
                if (j < n2) { s = s2; d = d2; }
                else { j -= n2; s = s3; d = d3; }
            }
        }
        float4 v = reinterpret_cast<const float4*>(s)[j];
        f16x4 h;
        h[0] = (f16)v.x; h[1] = (f16)v.y; h[2] = (f16)v.z; h[3] = (f16)v.w;
        reinterpret_cast<f16x4*>(d)[j] = h;
    }
}

// ---------------------------------------------------------------- helpers
DEV void stage16(void* lds, const void* g) {
    __builtin_amdgcn_global_load_lds(
        (const __attribute__((address_space(1))) void*)g,
        (__attribute__((address_space(3))) void*)lds,
        16, 0, 0);
}

// mt-outer-per-XCD block mapping: XCD x owns mt in [x*MT/8, (x+1)*MT/8);
// within the XCD, mt is the OUTER loop and nt sweeps inner, so the current
// A-tile (512KB) stays L2-resident across the whole nt sweep.
// Requires MT % 8 == 0; bijective for grid = MT * ntiles.
DEV void xcd_map(int bid, int MT, int ntiles, int& mt, int& nt) {
    const int x = bid & 7, q = bid >> 3;
    const int mpx = MT >> 3;
    mt = x * mpx + q / ntiles;
    nt = q % ntiles;
}

#define VMCNT(n) asm volatile("s_waitcnt vmcnt(" #n ")" ::: "memory")
#define BAR()    __builtin_amdgcn_s_barrier()
#define PRIO(p)  __builtin_amdgcn_s_setprio(p)

// ---------------------------------------------------------------- GEMM1: dual projection + bilinear fuse
// Block 256M x 128N-dual, BK=64; 8 waves (2M x 4N); wave 128M x 32N for R AND L.
// 4 phases/K-tile (quadrant walk); ONE barrier per phase, counted vmcnt(4).
// LDS: 2 bufs x (A 32KB + R 16KB + L 16KB) = 128KB.
__global__ __launch_bounds__(512, 2) void k_gemm_dual(
    const f16* __restrict__ Xh, const f16* __restrict__ Wr, const f16* __restrict__ Wl,
    const float* __restrict__ br, const float* __restrict__ bl,
    f16* __restrict__ inter, int MT)
{
    extern __shared__ __align__(16) char smem[];
    constexpr int NT = 16;                 // 1024 / 64
    constexpr int BUF = 65536;
    constexpr int OA = 0, OR = 32768, OL = 49152;

    int mt, nt;
    xcd_map(blockIdx.x, MT, HR / 128, mt, nt);
    const int m0 = mt * 256, n0 = nt * 128;
    const int tid = threadIdx.x;
    const int lane = tid & 63, wid = tid >> 6;
    const int wm = wid >> 2, wn = wid & 3;
    const int fr = lane & 15, fq = lane >> 4;
    const int xs = (fr & 7) << 4;
    const int dst = tid * 16;

    const int lr = tid >> 3;
    const int cb = ((tid & 7) << 4) ^ ((lr & 7) << 4);
    const char* pA0 = (const char*)Xh + (size_t)(m0 + lr)       * 2048 + cb;  // mi0,wm0
    const char* pA1 = (const char*)Xh + (size_t)(m0 + 128 + lr) * 2048 + cb;  // mi0,wm1
    const char* pA2 = (const char*)Xh + (size_t)(m0 + 64 + lr)  * 2048 + cb;  // mi1,wm0
    const char* pA3 = (const char*)Xh + (size_t)(m0 + 192 + lr) * 2048 + cb;  // mi1,wm1
    const char* pR0 = (const char*)Wr + (size_t)(n0 + lr)       * 2048 + cb;
    const char* pR1 = (const char*)Wr + (size_t)(n0 + 64 + lr)  * 2048 + cb;
    const char* pL0 = (const char*)Wl + (size_t)(n0 + lr)       * 2048 + cb;
    const char* pL1 = (const char*)Wl + (size_t)(n0 + 64 + lr)  * 2048 + cb;

#define D_AOFF(mi,mf,ks) (OA + ((mi)*128 + wm*64 + (mf)*16 + fr)*128 + ((((ks)*64) + fq*16) ^ xs))
#define D_ROFF(nf,ks)    (OR + (wn*32 + (nf)*16 + fr)*128 + ((((ks)*64) + fq*16) ^ xs))
#define D_LOFF(nf,ks)    (OL + (wn*32 + (nf)*16 + fr)*128 + ((((ks)*64) + fq*16) ^ xs))

    f16x8 a[4][2], bR[2][2], bL[2][2];
    f32x4 accR[8][2] = {};
    f32x4 accL[8][2] = {};

    // prologue: stage tile 0 in need-order
    stage16(smem + OA + dst, pA0);          stage16(smem + OA + 8192 + dst, pA1);
    stage16(smem + OR + dst, pR0);          stage16(smem + OR + 8192 + dst, pR1);
    stage16(smem + OL + dst, pL0);          stage16(smem + OL + 8192 + dst, pL1);
    stage16(smem + OA + 16384 + dst, pA2);  stage16(smem + OA + 24576 + dst, pA3);
    VMCNT(4);
    BAR();

    long ko = 128;
    for (int t = 0; t < NT; ++t) {
        char* base = smem + (t & 1) * BUF;
        char* nb   = smem + ((t & 1) ^ 1) * BUF;
        const bool pf = (t + 1) < NT;

        // ---- p1: (mi0, R)
#pragma unroll
        for (int mf = 0; mf < 4; ++mf)
#pragma unroll
            for (int ks = 0; ks < 2; ++ks)
                a[mf][ks] = *(const f16x8*)(base + D_AOFF(0, mf, ks));
#pragma unroll
        for (int nf = 0; nf < 2; ++nf)
#pragma unroll
            for (int ks = 0; ks < 2; ++ks)
                bR[nf][ks] = *(const f16x8*)(base + D_ROFF(nf, ks));
        if (pf) { stage16(nb + OA + dst, pA0 + ko); stage16(nb + OA + 8192 + dst, pA1 + ko); }
        PRIO(1);
#pragma unroll
        for (int mf = 0; mf < 4; ++mf)
#pragma unroll
            for (int nf = 0; nf < 2; ++nf)
#pragma unroll
                for (int ks = 0; ks < 2; ++ks)
                    accR[mf][nf] = __builtin_amdgcn_mfma_f32_16x16x32_f16(a[mf][ks], bR[nf][ks], accR[mf][nf], 0, 0, 0);
        PRIO(0);
        if (pf) { VMCNT(4); } else { VMCNT(2); }   // publish L0L1
        BAR();

        // ---- p2: (mi0, L)
#pragma unroll
        for (int nf = 0; nf < 2; ++nf)
#pragma unroll
            for (int ks = 0; ks < 2; ++ks)
                bL[nf][ks] = *(const f16x8*)(base + D_LOFF(nf, ks));
        if (pf) { stage16(nb + OR + dst, pR0 + ko); stage16(nb + OR + 8192 + dst, pR1 + ko); }
        PRIO(1);
#pragma unroll
        for (int mf = 0; mf < 4; ++mf)
#pragma unroll
            for (int nf = 0; nf < 2; ++nf)
#pragma unroll
                for (int ks = 0; ks < 2; ++ks)
                    accL[mf][nf] = __builtin_amdgcn_mfma_f32_16x16x32_f16(a[mf][ks], bL[nf][ks], accL[mf][nf], 0, 0, 0);
        PRIO(0);
        if (pf) { VMCNT(4); } else { VMCNT(0); }   // publish A2A3
        BAR();

        // ---- p3: (mi1, R)
#pragma unroll
        for (int mf = 0; mf < 4; ++mf)
#pragma unroll
            for (int ks = 0; ks < 2; ++ks)
                a[mf][ks] = *(const f16x8*)(base + D_AOFF(1, mf, ks));
        if (pf) { stage16(nb + OL + dst, pL0 + ko); stage16(nb + OL + 8192 + dst, pL1 + ko); }
        PRIO(1);
#pragma unroll
        for (int mf = 0; mf < 4; ++mf)
#pragma unroll
            for (int nf = 0; nf < 2; ++nf)
#pragma unroll
                for (int ks = 0; ks < 2; ++ks)
                    accR[4 + mf][nf] = __builtin_amdgcn_mfma_f32_16x16x32_f16(a[mf][ks], bR[nf][ks], accR[4 + mf][nf], 0, 0, 0);
        PRIO(0);
        BAR();

        // ---- p4: (mi1, L)
        if (pf) { stage16(nb + OA + 16384 + dst, pA2 + ko); stage16(nb + OA + 24576 + dst, pA3 + ko); }
        PRIO(1);
#pragma unroll
        for (int mf = 0; mf < 4; ++mf)
#pragma unroll
            for (int nf = 0; nf < 2; ++nf)
#pragma unroll
                for (int ks = 0; ks < 2; ++ks)
                    accL[4 + mf][nf] = __builtin_amdgcn_mfma_f32_16x16x32_f16(a[mf][ks], bL[nf][ks], accL[4 + mf][nf], 0, 0, 0);
        PRIO(0);
        if (pf) { VMCNT(4); }                      // publish next A0A1,R0R1
        BAR();

        ko += 128;
    }

    // epilogue: bias + bilinear product, fp16 out
#pragma unroll
    for (int nf = 0; nf < 2; ++nf) {
        const int gc = n0 + wn * 32 + nf * 16 + fr;
        const float brv = br[gc], blv = bl[gc];
#pragma unroll
        for (int mi = 0; mi < 2; ++mi)
#pragma unroll
            for (int mf = 0; mf < 4; ++mf) {
                const int gr0 = m0 + wm * 128 + mi * 64 + mf * 16 + fq * 4;
#pragma unroll
                for (int j = 0; j < 4; ++j) {
                    const float rv = accR[mi * 4 + mf][nf][j] + brv;
                    const float lv = accL[mi * 4 + mf][nf][j] + blv;
                    inter[(size_t)(gr0 + j) * HR + gc] = (f16)(rv * lv);
                }
            }
    }
#undef D_AOFF
#undef D_ROFF
#undef D_LOFF
}

// ---------------------------------------------------------------- GEMM2: expand + fused residual
// Block 256M x 256N, BK=64; 8 waves (2M x 4N); wave 128x64, quadrant walk.
// Epilogue writes E = Ain.Wt^T + be + resid (residual fused).
template <typename TR>
DEV void expand_body(const f16* Ain, const f16* Wt, const float* be,
                     const TR* resid, f16* E, int MT)
{
    extern __shared__ __align__(16) char smem[];
    constexpr int NT = 64;                 // 4096 / 64
    constexpr int BUF = 65536;
    constexpr int OA = 0, OB = 32768;

    int mt, nt;
    xcd_map(blockIdx.x, MT, D / 256, mt, nt);
    const int m0 = mt * 256, n0 = nt * 256;
    const int tid = threadIdx.x;
    const int lane = tid & 63, wid = tid >> 6;
    const int wm = wid >> 2, wn = wid & 3;
    const int fr = lane & 15, fq = lane >> 4;
    const int xs = (fr & 7) << 4;
    const int dst = tid * 16;

    const int lr = tid >> 3;
    const int cb = ((tid & 7) << 4) ^ ((lr & 7) << 4);
    const char* pA0 = (const char*)Ain + (size_t)(m0 + lr)       * 8192 + cb;
    const char* pA1 = (const char*)Ain + (size_t)(m0 + 128 + lr) * 8192 + cb;
    const char* pA2 = (const char*)Ain + (size_t)(m0 + 64 + lr)  * 8192 + cb;
    const char* pA3 = (const char*)Ain + (size_t)(m0 + 192 + lr) * 8192 + cb;
    const int r5 = lr & 31, wn2 = lr >> 5;
    const char* pB0 = (const char*)Wt + (size_t)(n0 + wn2 * 64 + r5)        * 8192 + cb;
    const char* pB1 = (const char*)Wt + (size_t)(n0 + (2 + wn2) * 64 + r5)  * 8192 + cb;
    const char* pB2 = (const char*)Wt + (size_t)(n0 + wn2 * 64 + 32 + r5)       * 8192 + cb;
    const char* pB3 = (const char*)Wt + (size_t)(n0 + (2 + wn2) * 64 + 32 + r5) * 8192 + cb;

#define E_AOFF(mi,mf,ks) (OA + ((mi)*128 + wm*64 + (mf)*16 + fr)*128 + ((((ks)*64) + fq*16) ^ xs))
#define E_BOFF(ni,nf,ks) (OB + ((ni)*128 + wn*32 + (nf)*16 + fr)*128 + ((((ks)*64) + fq*16) ^ xs))

    f16x8 a[4][2], b0[2][2], b1[2][2];
    f32x4 acc[8][4] = {};

    stage16(smem + OA + dst, pA0);          stage16(smem + OA + 8192 + dst, pA1);
    stage16(smem + OB + dst, pB0);          stage16(smem + OB + 8192 + dst, pB1);
    stage16(smem + OB + 16384 + dst, pB2);  stage16(smem + OB + 24576 + dst, pB3);
    stage16(smem + OA + 16384 + dst, pA2);  stage16(smem + OA + 24576 + dst, pA3);
    VMCNT(4);
    BAR();

    long ko = 128;
    for (int t = 0; t < NT; ++t) {
        char* base = smem + (t & 1) * BUF;
        char* nb   = smem + ((t & 1) ^ 1) * BUF;
        const bool pf = (t + 1) < NT;

        // ---- p1: (mi0, ni0)
#pragma unroll
        for (int mf = 0; mf < 4; ++mf)
#pragma unroll
            for (int ks = 0; ks < 2; ++ks)
                a[mf][ks] = *(const f16x8*)(base + E_AOFF(0, mf, ks));
#pragma unroll
        for (int nf = 0; nf < 2; ++nf)
#pragma unroll
            for (int ks = 0; ks < 2; ++ks)
                b0[nf][ks] = *(const f16x8*)(base + E_BOFF(0, nf, ks));
        if (pf) { stage16(nb + OA + dst, pA0 + ko); stage16(nb + OA + 8192 + dst, pA1 + ko); }
        PRIO(1);
#pragma unroll
        for (int mf = 0; mf < 4; ++mf)
#pragma unroll
            for (int nf = 0; nf < 2; ++nf)
#pragma unroll
                for (int ks = 0; ks < 2; ++ks)
                    acc[mf][nf] = __builtin_amdgcn_mfma_f32_16x16x32_f16(a[mf][ks], b0[nf][ks], acc[mf][nf], 0, 0, 0);
        PRIO(0);
        if (pf) { VMCNT(4); } else { VMCNT(2); }   // publish B2B3 (ni1)
        BAR();

        // ---- p2: (mi0, ni1)
#pragma unroll
        for (int nf = 0; nf < 2; ++nf)
#pragma unroll
            for (int ks = 0; ks < 2; ++ks)
                b1[nf][ks] = *(const f16x8*)(base + E_BOFF(1, nf, ks));
        if (pf) { stage16(nb + OB + dst, pB0 + ko); stage16(nb + OB + 8192 + dst, pB1 + ko); }
        PRIO(1);
#pragma unroll
        for (int mf = 0; mf < 4; ++mf)
#pragma unroll
            for (int nf = 0; nf < 2; ++nf)
#pragma unroll
                for (int ks = 0; ks < 2; ++ks)
                    acc[mf][2 + nf] = __builtin_amdgcn_mfma_f32_16x16x32_f16(a[mf][ks], b1[nf][ks], acc[mf][2 + nf], 0, 0, 0);
        PRIO(0);
        if (pf) { VMCNT(4); } else { VMCNT(0); }   // publish A2A3
        BAR();

        // ---- p3: (mi1, ni0)
#pragma unroll
        for (int mf = 0; mf < 4; ++mf)
#pragma unroll
            for (int ks = 0; ks < 2; ++ks)
                a[mf][ks] = *(const f16x8*)(base + E_AOFF(1, mf, ks));
        if (pf) { stage16(nb + OB + 16384 + dst, pB2 + ko); stage16(nb + OB + 24576 + dst, pB3 + ko); }
        PRIO(1);
#pragma unroll
        for (int mf = 0; mf < 4; ++mf)
#pragma unroll
            for (int nf = 0; nf < 2; ++nf)
#pragma unroll
                for (int ks = 0; ks < 2; ++ks)
                    acc[4 + mf][nf] = __builtin_amdgcn_mfma_f32_16x16x32_f16(a[mf][ks], b0[nf][ks], acc[4 + mf][nf], 0, 0, 0);
        PRIO(0);
        BAR();

        // ---- p4: (mi1, ni1)
        if (pf) { stage16(nb + OA + 16384 + dst, pA2 + ko); stage16(nb + OA + 24576 + dst, pA3 + ko); }
        PRIO(1);
#pragma unroll
        for (int mf = 0; mf < 4; ++mf)
#pragma unroll
            for (int nf = 0; nf < 2; ++nf)
#pragma unroll
                for (int ks = 0; ks < 2; ++ks)
                    acc[4 + mf][2 + nf] = __builtin_amdgcn_mfma_f32_16x16x32_f16(a[mf][ks], b1[nf][ks], acc[4 + mf][2 + nf], 0, 0, 0);
        PRIO(0);
        if (pf) { VMCNT(4); }                      // publish next A0A1,B0B1
        BAR();

        ko += 128;
    }

    // epilogue: bias + fused residual, fp16 out
#pragma unroll
    for (int ni = 0; ni < 2; ++ni)
#pragma unroll
        for (int nf = 0; nf < 2; ++nf) {
            const int gc = n0 + wn * 64 + ni * 32 + nf * 16 + fr;
            const float bev = be[gc];
#pragma unroll
            for (int mi = 0; mi < 2; ++mi)
#pragma unroll
                for (int mf = 0; mf < 4; ++mf) {
                    const int gr0 = m0 + wm * 128 + mi * 64 + mf * 16 + fq * 4;
#pragma unroll
                    for (int j = 0; j < 4; ++j) {
                        const float rv = (float)resid[(size_t)(gr0 + j) * D + gc];
                        E[(size_t)(gr0 + j) * D + gc] = (f16)(acc[mi * 4 + mf][ni * 2 + nf][j] + bev + rv);
                    }
                }
        }
#undef E_AOFF
#undef E_BOFF
}

__global__ __launch_bounds__(512, 2) void k_gemm_expand_f32r(
    const f16* __restrict__ Ain, const f16* __restrict__ Wt,
    const float* __restrict__ be, const float* __restrict__ resid,
    f16* __restrict__ E, int MT)
{ expand_body<float>(Ain, Wt, be, resid, E, MT); }

__global__ __launch_bounds__(512, 2) void k_gemm_expand_f16r(
    const f16* __restrict__ Ain, const f16* __restrict__ Wt,
    const float* __restrict__ be, const f16* __restrict__ resid,
    f16* __restrict__ E, int MT)
{ expand_body<f16>(Ain, Wt, be, resid, E, MT); }

// ---------------------------------------------------------------- in-place LayerNorm (residual already fused into EH)
__global__ __launch_bounds__(256) void k_ln(
    f16* __restrict__ EH, const float* __restrict__ g, const float* __restrict__ bb)
{
    const int wid = threadIdx.x >> 6, lane = threadIdx.x & 63;
    const int row = blockIdx.x * 4 + wid;
    f16* er = EH + (size_t)row * D;
    float v[16];
    float s = 0.f, sq = 0.f;
#pragma unroll
    for (int k = 0; k < 16; ++k) {
        const int c = lane + 64 * k;
        v[k] = (float)er[c];
        s += v[k];
        sq += v[k] * v[k];
    }
#pragma unroll
    for (int off = 32; off; off >>= 1) {
        s += __shfl_down(s, off);
        sq += __shfl_down(sq, off);
    }
    s = __shfl(s, 0);
    sq = __shfl(sq, 0);
    const float mu = s * (1.0f / D);
    const float var = sq * (1.0f / D) - mu * mu;
    const float rs = rsqrtf(var + 1e-5f);
#pragma unroll
    for (int k = 0; k < 16; ++k) {
        const int c = lane + 64 * k;
        const float o = (v[k] - mu) * rs * g[c] + bb[c];
        er[c] = (f16)o;
    }
}

// ---------------------------------------------------------------- fused LN2 + head: out = LN(EH) @ wf^T + bf
__global__ __launch_bounds__(256) void k_ln_head(
    const f16* __restrict__ EH, const float* __restrict__ g, const float* __restrict__ bb,
    const float* __restrict__ Wf, const float* __restrict__ bf, float* __restrict__ outp)
{
    __shared__ float wfs[NOUT * D];   // 40KB
    for (int i = threadIdx.x; i < NOUT * D; i += 256) wfs[i] = Wf[i];
    __syncthreads();
    const int wid = threadIdx.x >> 6, lane = threadIdx.x & 63;
    const int row = blockIdx.x * 4 + wid;
    const f16* er = EH + (size_t)row * D;
    float v[16];
    float s = 0.f, sq = 0.f;
#pragma unroll
    for (int k = 0; k < 16; ++k) {
        const int c = lane + 64 * k;
        v[k] = (float)er[c];
        s += v[k];
        sq += v[k] * v[k];
    }
#pragma unroll
    for (int off = 32; off; off >>= 1) {
        s += __shfl_down(s, off);
        sq += __shfl_down(sq, off);
    }
    s = __shfl(s, 0);
    sq = __shfl(sq, 0);
    const float mu = s * (1.0f / D);
    const float var = sq * (1.0f / D) - mu * mu;
    const float rs = rsqrtf(var + 1e-5f);
#pragma unroll
    for (int k = 0; k < 16; ++k) {
        const int c = lane + 64 * k;
        v[k] = (v[k] - mu) * rs * g[c] + bb[c];
    }
#pragma unroll
    for (int j = 0; j < NOUT; ++j) {
        float p = 0.f;
#pragma unroll
        for (int k = 0; k < 16; ++k) p += v[k] * wfs[j * D + lane + 64 * k];
#pragma unroll
        for (int off = 32; off; off >>= 1) p += __shfl_down(p, off);
        if (lane == 0) outp[(size_t)row * NOUT + j] = p + bf[j];
    }
}

// ---------------------------------------------------------------- launch
extern "C" void kernel_launch(void* const* d_in, const int* in_sizes, int n_in,
                              void* d_out, int out_size, void* d_ws, size_t ws_size,
                              hipStream_t stream) {
    (void)in_sizes; (void)n_in; (void)out_size;
    const float* x   = (const float*)d_in[0];
    const float* wr1 = (const float*)d_in[1];
    const float* br1 = (const float*)d_in[2];
    const float* wl1 = (const float*)d_in[3];
    const float* bl1 = (const float*)d_in[4];
    const float* we1 = (const float*)d_in[5];
    const float* be1 = (const float*)d_in[6];
    const float* g1  = (const float*)d_in[7];
    const float* b1  = (const float*)d_in[8];
    const float* wr2 = (const float*)d_in[9];
    const float* br2 = (const float*)d_in[10];
    const float* wl2 = (const float*)d_in[11];
    const float* bl2 = (const float*)d_in[12];
    const float* we2 = (const float*)d_in[13];
    const float* be2 = (const float*)d_in[14];
    const float* g2  = (const float*)d_in[15];
    const float* b2  = (const float*)d_in[16];
    const float* wf  = (const float*)d_in[17];
    const float* bf  = (const float*)d_in[18];
    float* outp = (float*)d_out;

    constexpr size_t SZ_W16 = (size_t)HR * D * sizeof(f16);    // 8 MB
    constexpr size_t SZ_A16 = (size_t)BATCH * D * sizeof(f16); // 32 MB
    constexpr int SMEM = 2 * 65536;

    hipFuncSetAttribute((const void*)k_gemm_dual,        hipFuncAttributeMaxDynamicSharedMemorySize, SMEM);
    hipFuncSetAttribute((const void*)k_gemm_expand_f32r, hipFuncAttributeMaxDynamicSharedMemorySize, SMEM);
    hipFuncSetAttribute((const void*)k_gemm_expand_f16r, hipFuncAttributeMaxDynamicSharedMemorySize, SMEM);

    // workspace: weights(24MB) + xh(32MB) + EH(32MB) = 88MB base, rest = inter chunk
    char* p = (char*)d_ws;
    f16* wrh = (f16*)p; p += SZ_W16;
    f16* wlh = (f16*)p; p += SZ_W16;
    f16* weh = (f16*)p; p += SZ_W16;
    f16* xh  = (f16*)p; p += SZ_A16;   // f16 of x (dual-1 input only)
    f16* EH  = (f16*)p; p += SZ_A16;   // E1+x -> h1 (in-place LN) -> E2+h1 -> h2
    f16* interh = (f16*)p;
    const size_t base = (size_t)(p - (char*)d_ws);
    const size_t avail = ws_size > base ? ws_size - base : 0;

    int CH = 2048;
    if ((size_t)16384 * HR * sizeof(f16) <= avail) CH = 16384;
    else if ((size_t)8192 * HR * sizeof(f16) <= avail) CH = 8192;
    else if ((size_t)4096 * HR * sizeof(f16) <= avail) CH = 4096;

    const int nch = BATCH / CH;
    const int MT = CH / 256;
    const int gDual = MT * (HR / 128);
    const int gExp  = MT * (D / 256);

    constexpr int NW4 = HR * D / 4;
    k_conv4<<<2048, 256, 0, stream>>>(x, xh, BATCH * D / 4,
                                      wr1, wrh, NW4, wl1, wlh, NW4, we1, weh, NW4);

    // ---- block 1 (residual x fused into expand epilogue)
    for (int c = 0; c < nch; ++c) {
        k_gemm_dual<<<gDual, 512, SMEM, stream>>>(xh + (size_t)c * CH * D, wrh, wlh, br1, bl1, interh, MT);
        k_gemm_expand_f32r<<<gExp, 512, SMEM, stream>>>(interh, weh, be1, x + (size_t)c * CH * D,
                                                        EH + (size_t)c * CH * D, MT);
    }
    k_ln<<<BATCH / 4, 256, 0, stream>>>(EH, g1, b1);   // EH := h1

    k_conv4<<<1536, 256, 0, stream>>>(wr2, wrh, NW4, wl2, wlh, NW4, we2, weh, NW4,
                                      nullptr, nullptr, 0);

    // ---- block 2 (residual h1 fused; EH overwritten chunk-by-chunk after its dual read)
    for (int c = 0; c < nch; ++c) {
        k_gemm_dual<<<gDual, 512, SMEM, stream>>>(EH + (size_t)c * CH * D, wrh, wlh, br2, bl2, interh, MT);
        k_gemm_expand_f16r<<<gExp, 512, SMEM, stream>>>(interh, weh, be2, EH + (size_t)c * CH * D,
                                                        EH + (size_t)c * CH * D, MT);
    }

    // ---- fused LN2 + head
    k_ln_head<<<BATCH / 4, 256, 0, stream>>>(EH, g2, b2, wf, bf, outp);
}

// Round 11
// 786.863 us; speedup vs baseline: 1.0495x; 1.0495x over previous
//
#include <hip/hip_runtime.h>
#include <hip/hip_fp16.h>

#define DEV static __device__ __forceinline__

typedef _Float16 f16;
typedef _Float16 f16x8 __attribute__((ext_vector_type(8)));
typedef _Float16 f16x4 __attribute__((ext_vector_type(4)));
typedef float f32x4 __attribute__((ext_vector_type(4)));

constexpr int BATCH = 16384;
constexpr int D = 1024;
constexpr int HR = 4096;
constexpr int NOUT = 10;

// ---------------------------------------------------------------- fused converts (4 segments, any may be empty)
__global__ void k_conv4(const float* __restrict__ s0, f16* __restrict__ d0, int n0,
                        const float* __restrict__ s1, f16* __restrict__ d1, int n1,
                        const float* __restrict__ s2, f16* __restrict__ d2, int n2,
                        const float* __restrict__ s3, f16* __restrict__ d3, int n3) {
    int i = blockIdx.x * blockDim.x + threadIdx.x;
    const int st = gridDim.x * blockDim.x;
    const int tot = n0 + n1 + n2 + n3;
    for (; i < tot; i += st) {
        const float* s; f16* d; int j = i;
        if (j < n0) { s = s0; d = d0; }
        else {
            j -= n0;
            if (j < n1) { s = s1; d = d1; }
            else {
                j -= n1;
                if (j < n2) { s = s2; d = d2; }
                else { j -= n2; s = s3; d = d3; }
            }
        }
        float4 v = reinterpret_cast<const float4*>(s)[j];
        f16x4 h;
        h[0] = (f16)v.x; h[1] = (f16)v.y; h[2] = (f16)v.z; h[3] = (f16)v.w;
        reinterpret_cast<f16x4*>(d)[j] = h;
    }
}

// ---------------------------------------------------------------- helpers
DEV void stage16(void* lds, const void* g) {
    __builtin_amdgcn_global_load_lds(
        (const __attribute__((address_space(1))) void*)g,
        (__attribute__((address_space(3))) void*)lds,
        16, 0, 0);
}

// r8-proven XCD map: XCD x owns mt in [x*MT/8, (x+1)*MT/8); mt sweeps INNER
// (consecutive blocks on an XCD share the nt / B-tile, and the XCD's 4MB
// A-panel stays warm across the nt sweep).  Measured: dual FETCH 197MB.
// Requires MT % 8 == 0; bijective.
DEV void xcd_map(int bid, int MT, int& mt, int& nt) {
    const int x = bid & 7, q = bid >> 3;
    const int mpx = MT >> 3;
    nt = q / mpx;
    mt = x * mpx + (q % mpx);
}

#define VMCNT(n) asm volatile("s_waitcnt vmcnt(" #n ")" ::: "memory")
#define BAR()    __builtin_amdgcn_s_barrier()
#define PRIO(p)  __builtin_amdgcn_s_setprio(p)

// ---------------------------------------------------------------- GEMM1: dual projection + bilinear fuse
// Block 256M x 128N-dual, BK=64; 8 waves (2M x 4N); wave 128M x 32N for R AND L.
// 4 phases/K-tile (quadrant walk); ONE barrier per phase, counted vmcnt(4).
// LDS: 2 bufs x (A 32KB + R 16KB + L 16KB) = 128KB.
__global__ __launch_bounds__(512, 2) void k_gemm_dual(
    const f16* __restrict__ Xh, const f16* __restrict__ Wr, const f16* __restrict__ Wl,
    const float* __restrict__ br, const float* __restrict__ bl,
    f16* __restrict__ inter, int MT)
{
    extern __shared__ __align__(16) char smem[];
    constexpr int NT = 16;                 // 1024 / 64
    constexpr int BUF = 65536;
    constexpr int OA = 0, OR = 32768, OL = 49152;

    int mt, nt;
    xcd_map(blockIdx.x, MT, mt, nt);
    const int m0 = mt * 256, n0 = nt * 128;
    const int tid = threadIdx.x;
    const int lane = tid & 63, wid = tid >> 6;
    const int wm = wid >> 2, wn = wid & 3;
    const int fr = lane & 15, fq = lane >> 4;
    const int xs = (fr & 7) << 4;
    const int dst = tid * 16;

    const int lr = tid >> 3;
    const int cb = ((tid & 7) << 4) ^ ((lr & 7) << 4);
    const char* pA0 = (const char*)Xh + (size_t)(m0 + lr)       * 2048 + cb;  // mi0,wm0
    const char* pA1 = (const char*)Xh + (size_t)(m0 + 128 + lr) * 2048 + cb;  // mi0,wm1
    const char* pA2 = (const char*)Xh + (size_t)(m0 + 64 + lr)  * 2048 + cb;  // mi1,wm0
    const char* pA3 = (const char*)Xh + (size_t)(m0 + 192 + lr) * 2048 + cb;  // mi1,wm1
    const char* pR0 = (const char*)Wr + (size_t)(n0 + lr)       * 2048 + cb;
    const char* pR1 = (const char*)Wr + (size_t)(n0 + 64 + lr)  * 2048 + cb;
    const char* pL0 = (const char*)Wl + (size_t)(n0 + lr)       * 2048 + cb;
    const char* pL1 = (const char*)Wl + (size_t)(n0 + 64 + lr)  * 2048 + cb;

#define D_AOFF(mi,mf,ks) (OA + ((mi)*128 + wm*64 + (mf)*16 + fr)*128 + ((((ks)*64) + fq*16) ^ xs))
#define D_ROFF(nf,ks)    (OR + (wn*32 + (nf)*16 + fr)*128 + ((((ks)*64) + fq*16) ^ xs))
#define D_LOFF(nf,ks)    (OL + (wn*32 + (nf)*16 + fr)*128 + ((((ks)*64) + fq*16) ^ xs))

    f16x8 a[4][2], bR[2][2], bL[2][2];
    f32x4 accR[8][2] = {};
    f32x4 accL[8][2] = {};

    // prologue: stage tile 0 in need-order
    stage16(smem + OA + dst, pA0);          stage16(smem + OA + 8192 + dst, pA1);
    stage16(smem + OR + dst, pR0);          stage16(smem + OR + 8192 + dst, pR1);
    stage16(smem + OL + dst, pL0);          stage16(smem + OL + 8192 + dst, pL1);
    stage16(smem + OA + 16384 + dst, pA2);  stage16(smem + OA + 24576 + dst, pA3);
    VMCNT(4);
    BAR();

    long ko = 128;
    for (int t = 0; t < NT; ++t) {
        char* base = smem + (t & 1) * BUF;
        char* nb   = smem + ((t & 1) ^ 1) * BUF;
        const bool pf = (t + 1) < NT;

        // ---- p1: (mi0, R)
#pragma unroll
        for (int mf = 0; mf < 4; ++mf)
#pragma unroll
            for (int ks = 0; ks < 2; ++ks)
                a[mf][ks] = *(const f16x8*)(base + D_AOFF(0, mf, ks));
#pragma unroll
        for (int nf = 0; nf < 2; ++nf)
#pragma unroll
            for (int ks = 0; ks < 2; ++ks)
                bR[nf][ks] = *(const f16x8*)(base + D_ROFF(nf, ks));
        if (pf) { stage16(nb + OA + dst, pA0 + ko); stage16(nb + OA + 8192 + dst, pA1 + ko); }
        PRIO(1);
#pragma unroll
        for (int mf = 0; mf < 4; ++mf)
#pragma unroll
            for (int nf = 0; nf < 2; ++nf)
#pragma unroll
                for (int ks = 0; ks < 2; ++ks)
                    accR[mf][nf] = __builtin_amdgcn_mfma_f32_16x16x32_f16(a[mf][ks], bR[nf][ks], accR[mf][nf], 0, 0, 0);
        PRIO(0);
        if (pf) { VMCNT(4); } else { VMCNT(2); }   // publish L0L1
        BAR();

        // ---- p2: (mi0, L)
#pragma unroll
        for (int nf = 0; nf < 2; ++nf)
#pragma unroll
            for (int ks = 0; ks < 2; ++ks)
                bL[nf][ks] = *(const f16x8*)(base + D_LOFF(nf, ks));
        if (pf) { stage16(nb + OR + dst, pR0 + ko); stage16(nb + OR + 8192 + dst, pR1 + ko); }
        PRIO(1);
#pragma unroll
        for (int mf = 0; mf < 4; ++mf)
#pragma unroll
            for (int nf = 0; nf < 2; ++nf)
#pragma unroll
                for (int ks = 0; ks < 2; ++ks)
                    accL[mf][nf] = __builtin_amdgcn_mfma_f32_16x16x32_f16(a[mf][ks], bL[nf][ks], accL[mf][nf], 0, 0, 0);
        PRIO(0);
        if (pf) { VMCNT(4); } else { VMCNT(0); }   // publish A2A3
        BAR();

        // ---- p3: (mi1, R)
#pragma unroll
        for (int mf = 0; mf < 4; ++mf)
#pragma unroll
            for (int ks = 0; ks < 2; ++ks)
                a[mf][ks] = *(const f16x8*)(base + D_AOFF(1, mf, ks));
        if (pf) { stage16(nb + OL + dst, pL0 + ko); stage16(nb + OL + 8192 + dst, pL1 + ko); }
        PRIO(1);
#pragma unroll
        for (int mf = 0; mf < 4; ++mf)
#pragma unroll
            for (int nf = 0; nf < 2; ++nf)
#pragma unroll
                for (int ks = 0; ks < 2; ++ks)
                    accR[4 + mf][nf] = __builtin_amdgcn_mfma_f32_16x16x32_f16(a[mf][ks], bR[nf][ks], accR[4 + mf][nf], 0, 0, 0);
        PRIO(0);
        BAR();

        // ---- p4: (mi1, L)
        if (pf) { stage16(nb + OA + 16384 + dst, pA2 + ko); stage16(nb + OA + 24576 + dst, pA3 + ko); }
        PRIO(1);
#pragma unroll
        for (int mf = 0; mf < 4; ++mf)
#pragma unroll
            for (int nf = 0; nf < 2; ++nf)
#pragma unroll
                for (int ks = 0; ks < 2; ++ks)
                    accL[4 + mf][nf] = __builtin_amdgcn_mfma_f32_16x16x32_f16(a[mf][ks], bL[nf][ks], accL[4 + mf][nf], 0, 0, 0);
        PRIO(0);
        if (pf) { VMCNT(4); }                      // publish next A0A1,R0R1
        BAR();

        ko += 128;
    }

    // epilogue: bias + bilinear product, fp16 out
#pragma unroll
    for (int nf = 0; nf < 2; ++nf) {
        const int gc = n0 + wn * 32 + nf * 16 + fr;
        const float brv = br[gc], blv = bl[gc];
#pragma unroll
        for (int mi = 0; mi < 2; ++mi)
#pragma unroll
            for (int mf = 0; mf < 4; ++mf) {
                const int gr0 = m0 + wm * 128 + mi * 64 + mf * 16 + fq * 4;
#pragma unroll
                for (int j = 0; j < 4; ++j) {
                    const float rv = accR[mi * 4 + mf][nf][j] + brv;
                    const float lv = accL[mi * 4 + mf][nf][j] + blv;
                    inter[(size_t)(gr0 + j) * HR + gc] = (f16)(rv * lv);
                }
            }
    }
#undef D_AOFF
#undef D_ROFF
#undef D_LOFF
}

// ---------------------------------------------------------------- GEMM2: expand + fused residual
// Block 256M x 256N, BK=64; 8 waves (2M x 4N); wave 128x64, quadrant walk.
// Epilogue writes E = Ain.Wt^T + be + resid (residual fused).
template <typename TR>
DEV void expand_body(const f16* Ain, const f16* Wt, const float* be,
                     const TR* resid, f16* E, int MT)
{
    extern __shared__ __align__(16) char smem[];
    constexpr int NT = 64;                 // 4096 / 64
    constexpr int BUF = 65536;
    constexpr int OA = 0, OB = 32768;

    int mt, nt;
    xcd_map(blockIdx.x, MT, mt, nt);
    const int m0 = mt * 256, n0 = nt * 256;
    const int tid = threadIdx.x;
    const int lane = tid & 63, wid = tid >> 6;
    const int wm = wid >> 2, wn = wid & 3;
    const int fr = lane & 15, fq = lane >> 4;
    const int xs = (fr & 7) << 4;
    const int dst = tid * 16;

    const int lr = tid >> 3;
    const int cb = ((tid & 7) << 4) ^ ((lr & 7) << 4);
    const char* pA0 = (const char*)Ain + (size_t)(m0 + lr)       * 8192 + cb;
    const char* pA1 = (const char*)Ain + (size_t)(m0 + 128 + lr) * 8192 + cb;
    const char* pA2 = (const char*)Ain + (size_t)(m0 + 64 + lr)  * 8192 + cb;
    const char* pA3 = (const char*)Ain + (size_t)(m0 + 192 + lr) * 8192 + cb;
    const int r5 = lr & 31, wn2 = lr >> 5;
    const char* pB0 = (const char*)Wt + (size_t)(n0 + wn2 * 64 + r5)        * 8192 + cb;
    const char* pB1 = (const char*)Wt + (size_t)(n0 + (2 + wn2) * 64 + r5)  * 8192 + cb;
    const char* pB2 = (const char*)Wt + (size_t)(n0 + wn2 * 64 + 32 + r5)       * 8192 + cb;
    const char* pB3 = (const char*)Wt + (size_t)(n0 + (2 + wn2) * 64 + 32 + r5) * 8192 + cb;

#define E_AOFF(mi,mf,ks) (OA + ((mi)*128 + wm*64 + (mf)*16 + fr)*128 + ((((ks)*64) + fq*16) ^ xs))
#define E_BOFF(ni,nf,ks) (OB + ((ni)*128 + wn*32 + (nf)*16 + fr)*128 + ((((ks)*64) + fq*16) ^ xs))

    f16x8 a[4][2], b0[2][2], b1[2][2];
    f32x4 acc[8][4] = {};

    stage16(smem + OA + dst, pA0);          stage16(smem + OA + 8192 + dst, pA1);
    stage16(smem + OB + dst, pB0);          stage16(smem + OB + 8192 + dst, pB1);
    stage16(smem + OB + 16384 + dst, pB2);  stage16(smem + OB + 24576 + dst, pB3);
    stage16(smem + OA + 16384 + dst, pA2);  stage16(smem + OA + 24576 + dst, pA3);
    VMCNT(4);
    BAR();

    long ko = 128;
    for (int t = 0; t < NT; ++t) {
        char* base = smem + (t & 1) * BUF;
        char* nb   = smem + ((t & 1) ^ 1) * BUF;
        const bool pf = (t + 1) < NT;

        // ---- p1: (mi0, ni0)
#pragma unroll
        for (int mf = 0; mf < 4; ++mf)
#pragma unroll
            for (int ks = 0; ks < 2; ++ks)
                a[mf][ks] = *(const f16x8*)(base + E_AOFF(0, mf, ks));
#pragma unroll
        for (int nf = 0; nf < 2; ++nf)
#pragma unroll
            for (int ks = 0; ks < 2; ++ks)
                b0[nf][ks] = *(const f16x8*)(base + E_BOFF(0, nf, ks));
        if (pf) { stage16(nb + OA + dst, pA0 + ko); stage16(nb + OA + 8192 + dst, pA1 + ko); }
        PRIO(1);
#pragma unroll
        for (int mf = 0; mf < 4; ++mf)
#pragma unroll
            for (int nf = 0; nf < 2; ++nf)
#pragma unroll
                for (int ks = 0; ks < 2; ++ks)
                    acc[mf][nf] = __builtin_amdgcn_mfma_f32_16x16x32_f16(a[mf][ks], b0[nf][ks], acc[mf][nf], 0, 0, 0);
        PRIO(0);
        if (pf) { VMCNT(4); } else { VMCNT(2); }   // publish B2B3 (ni1)
        BAR();

        // ---- p2: (mi0, ni1)
#pragma unroll
        for (int nf = 0; nf < 2; ++nf)
#pragma unroll
            for (int ks = 0; ks < 2; ++ks)
                b1[nf][ks] = *(const f16x8*)(base + E_BOFF(1, nf, ks));
        if (pf) { stage16(nb + OB + dst, pB0 + ko); stage16(nb + OB + 8192 + dst, pB1 + ko); }
        PRIO(1);
#pragma unroll
        for (int mf = 0; mf < 4; ++mf)
#pragma unroll
            for (int nf = 0; nf < 2; ++nf)
#pragma unroll
                for (int ks = 0; ks < 2; ++ks)
                    acc[mf][2 + nf] = __builtin_amdgcn_mfma_f32_16x16x32_f16(a[mf][ks], b1[nf][ks], acc[mf][2 + nf], 0, 0, 0);
        PRIO(0);
        if (pf) { VMCNT(4); } else { VMCNT(0); }   // publish A2A3
        BAR();

        // ---- p3: (mi1, ni0)
#pragma unroll
        for (int mf = 0; mf < 4; ++mf)
#pragma unroll
            for (int ks = 0; ks < 2; ++ks)
                a[mf][ks] = *(const f16x8*)(base + E_AOFF(1, mf, ks));
        if (pf) { stage16(nb + OB + 16384 + dst, pB2 + ko); stage16(nb + OB + 24576 + dst, pB3 + ko); }
        PRIO(1);
#pragma unroll
        for (int mf = 0; mf < 4; ++mf)
#pragma unroll
            for (int nf = 0; nf < 2; ++nf)
#pragma unroll
                for (int ks = 0; ks < 2; ++ks)
                    acc[4 + mf][nf] = __builtin_amdgcn_mfma_f32_16x16x32_f16(a[mf][ks], b0[nf][ks], acc[4 + mf][nf], 0, 0, 0);
        PRIO(0);
        BAR();

        // ---- p4: (mi1, ni1)
        if (pf) { stage16(nb + OA + 16384 + dst, pA2 + ko); stage16(nb + OA + 24576 + dst, pA3 + ko); }
        PRIO(1);
#pragma unroll
        for (int mf = 0; mf < 4; ++mf)
#pragma unroll
            for (int nf = 0; nf < 2; ++nf)
#pragma unroll
                for (int ks = 0; ks < 2; ++ks)
                    acc[4 + mf][2 + nf] = __builtin_amdgcn_mfma_f32_16x16x32_f16(a[mf][ks], b1[nf][ks], acc[4 + mf][2 + nf], 0, 0, 0);
        PRIO(0);
        if (pf) { VMCNT(4); }                      // publish next A0A1,B0B1
        BAR();

        ko += 128;
    }

    // epilogue: bias + fused residual, fp16 out
#pragma unroll
    for (int ni = 0; ni < 2; ++ni)
#pragma unroll
        for (int nf = 0; nf < 2; ++nf) {
            const int gc = n0 + wn * 64 + ni * 32 + nf * 16 + fr;
            const float bev = be[gc];
#pragma unroll
            for (int mi = 0; mi < 2; ++mi)
#pragma unroll
                for (int mf = 0; mf < 4; ++mf) {
                    const int gr0 = m0 + wm * 128 + mi * 64 + mf * 16 + fq * 4;
#pragma unroll
                    for (int j = 0; j < 4; ++j) {
                        const float rv = (float)resid[(size_t)(gr0 + j) * D + gc];
                        E[(size_t)(gr0 + j) * D + gc] = (f16)(acc[mi * 4 + mf][ni * 2 + nf][j] + bev + rv);
                    }
                }
        }
#undef E_AOFF
#undef E_BOFF
}

__global__ __launch_bounds__(512, 2) void k_gemm_expand_f32r(
    const f16* __restrict__ Ain, const f16* __restrict__ Wt,
    const float* __restrict__ be, const float* __restrict__ resid,
    f16* __restrict__ E, int MT)
{ expand_body<float>(Ain, Wt, be, resid, E, MT); }

__global__ __launch_bounds__(512, 2) void k_gemm_expand_f16r(
    const f16* __restrict__ Ain, const f16* __restrict__ Wt,
    const float* __restrict__ be, const f16* __restrict__ resid,
    f16* __restrict__ E, int MT)
{ expand_body<f16>(Ain, Wt, be, resid, E, MT); }

// ---------------------------------------------------------------- in-place LayerNorm (residual already fused into EH)
__global__ __launch_bounds__(256) void k_ln(
    f16* __restrict__ EH, const float* __restrict__ g, const float* __restrict__ bb)
{
    const int wid = threadIdx.x >> 6, lane = threadIdx.x & 63;
    const int row = blockIdx.x * 4 + wid;
    f16* er = EH + (size_t)row * D;
    float v[16];
    float s = 0.f, sq = 0.f;
#pragma unroll
    for (int k = 0; k < 16; ++k) {
        const int c = lane + 64 * k;
        v[k] = (float)er[c];
        s += v[k];
        sq += v[k] * v[k];
    }
#pragma unroll
    for (int off = 32; off; off >>= 1) {
        s += __shfl_down(s, off);
        sq += __shfl_down(sq, off);
    }
    s = __shfl(s, 0);
    sq = __shfl(sq, 0);
    const float mu = s * (1.0f / D);
    const float var = sq * (1.0f / D) - mu * mu;
    const float rs = rsqrtf(var + 1e-5f);
#pragma unroll
    for (int k = 0; k < 16; ++k) {
        const int c = lane + 64 * k;
        const float o = (v[k] - mu) * rs * g[c] + bb[c];
        er[c] = (f16)o;
    }
}

// ---------------------------------------------------------------- fused LN2 + head: out = LN(EH) @ wf^T + bf
__global__ __launch_bounds__(256) void k_ln_head(
    const f16* __restrict__ EH, const float* __restrict__ g, const float* __restrict__ bb,
    const float* __restrict__ Wf, const float* __restrict__ bf, float* __restrict__ outp)
{
    __shared__ float wfs[NOUT * D];   // 40KB
    for (int i = threadIdx.x; i < NOUT * D; i += 256) wfs[i] = Wf[i];
    __syncthreads();
    const int wid = threadIdx.x >> 6, lane = threadIdx.x & 63;
    const int row = blockIdx.x * 4 + wid;
    const f16* er = EH + (size_t)row * D;
    float v[16];
    float s = 0.f, sq = 0.f;
#pragma unroll
    for (int k = 0; k < 16; ++k) {
        const int c = lane + 64 * k;
        v[k] = (float)er[c];
        s += v[k];
        sq += v[k] * v[k];
    }
#pragma unroll
    for (int off = 32; off; off >>= 1) {
        s += __shfl_down(s, off);
        sq += __shfl_down(sq, off);
    }
    s = __shfl(s, 0);
    sq = __shfl(sq, 0);
    const float mu = s * (1.0f / D);
    const float var = sq * (1.0f / D) - mu * mu;
    const float rs = rsqrtf(var + 1e-5f);
#pragma unroll
    for (int k = 0; k < 16; ++k) {
        const int c = lane + 64 * k;
        v[k] = (v[k] - mu) * rs * g[c] + bb[c];
    }
#pragma unroll
    for (int j = 0; j < NOUT; ++j) {
        float p = 0.f;
#pragma unroll
        for (int k = 0; k < 16; ++k) p += v[k] * wfs[j * D + lane + 64 * k];
#pragma unroll
        for (int off = 32; off; off >>= 1) p += __shfl_down(p, off);
        if (lane == 0) outp[(size_t)row * NOUT + j] = p + bf[j];
    }
}

// ---------------------------------------------------------------- launch
extern "C" void kernel_launch(void* const* d_in, const int* in_sizes, int n_in,
                              void* d_out, int out_size, void* d_ws, size_t ws_size,
                              hipStream_t stream) {
    (void)in_sizes; (void)n_in; (void)out_size;
    const float* x   = (const float*)d_in[0];
    const float* wr1 = (const float*)d_in[1];
    const float* br1 = (const float*)d_in[2];
    const float* wl1 = (const float*)d_in[3];
    const float* bl1 = (const float*)d_in[4];
    const float* we1 = (const float*)d_in[5];
    const float* be1 = (const float*)d_in[6];
    const float* g1  = (const float*)d_in[7];
    const float* b1  = (const float*)d_in[8];
    const float* wr2 = (const float*)d_in[9];
    const float* br2 = (const float*)d_in[10];
    const float* wl2 = (const float*)d_in[11];
    const float* bl2 = (const float*)d_in[12];
    const float* we2 = (const float*)d_in[13];
    const float* be2 = (const float*)d_in[14];
    const float* g2  = (const float*)d_in[15];
    const float* b2  = (const float*)d_in[16];
    const float* wf  = (const float*)d_in[17];
    const float* bf  = (const float*)d_in[18];
    float* outp = (float*)d_out;

    constexpr size_t SZ_W16 = (size_t)HR * D * sizeof(f16);    // 8 MB
    constexpr size_t SZ_A16 = (size_t)BATCH * D * sizeof(f16); // 32 MB
    constexpr int SMEM = 2 * 65536;

    hipFuncSetAttribute((const void*)k_gemm_dual,        hipFuncAttributeMaxDynamicSharedMemorySize, SMEM);
    hipFuncSetAttribute((const void*)k_gemm_expand_f32r, hipFuncAttributeMaxDynamicSharedMemorySize, SMEM);
    hipFuncSetAttribute((const void*)k_gemm_expand_f16r, hipFuncAttributeMaxDynamicSharedMemorySize, SMEM);

    // workspace: weights(24MB) + xh(32MB) + EH(32MB) = 88MB base, rest = inter chunk
    char* p = (char*)d_ws;
    f16* wrh = (f16*)p; p += SZ_W16;
    f16* wlh = (f16*)p; p += SZ_W16;
    f16* weh = (f16*)p; p += SZ_W16;
    f16* xh  = (f16*)p; p += SZ_A16;   // f16 of x (dual-1 input only)
    f16* EH  = (f16*)p; p += SZ_A16;   // E1+x -> h1 (in-place LN) -> E2+h1 -> h2
    f16* interh = (f16*)p;
    const size_t base = (size_t)(p - (char*)d_ws);
    const size_t avail = ws_size > base ? ws_size - base : 0;

    int CH = 2048;
    if ((size_t)16384 * HR * sizeof(f16) <= avail) CH = 16384;
    else if ((size_t)8192 * HR * sizeof(f16) <= avail) CH = 8192;
    else if ((size_t)4096 * HR * sizeof(f16) <= avail) CH = 4096;

    const int nch = BATCH / CH;
    const int MT = CH / 256;
    const int gDual = MT * (HR / 128);
    const int gExp  = MT * (D / 256);

    constexpr int NW4 = HR * D / 4;
    k_conv4<<<2048, 256, 0, stream>>>(x, xh, BATCH * D / 4,
                                      wr1, wrh, NW4, wl1, wlh, NW4, we1, weh, NW4);

    // ---- block 1 (residual x fused into expand epilogue)
    for (int c = 0; c < nch; ++c) {
        k_gemm_dual<<<gDual, 512, SMEM, stream>>>(xh + (size_t)c * CH * D, wrh, wlh, br1, bl1, interh, MT);
        k_gemm_expand_f32r<<<gExp, 512, SMEM, stream>>>(interh, weh, be1, x + (size_t)c * CH * D,
                                                        EH + (size_t)c * CH * D, MT);
    }
    k_ln<<<BATCH / 4, 256, 0, stream>>>(EH, g1, b1);   // EH := h1

    k_conv4<<<1536, 256, 0, stream>>>(wr2, wrh, NW4, wl2, wlh, NW4, we2, weh, NW4,
                                      nullptr, nullptr, 0);

    // ---- block 2 (residual h1 fused; EH overwritten chunk-by-chunk after its dual read)
    for (int c = 0; c < nch; ++c) {
        k_gemm_dual<<<gDual, 512, SMEM, stream>>>(EH + (size_t)c * CH * D, wrh, wlh, br2, bl2, interh, MT);
        k_gemm_expand_f16r<<<gExp, 512, SMEM, stream>>>(interh, weh, be2, EH + (size_t)c * CH * D,
                                                        EH + (size_t)c * CH * D, MT);
    }

    // ---- fused LN2 + head
    k_ln_head<<<BATCH / 4, 256, 0, stream>>>(EH, g2, b2, wf, bf, outp);
}